// Round 7
// baseline (287.619 us; speedup 1.0000x reference)
//
#include <hip/hip_runtime.h>
#include <hip/hip_bf16.h>

#define N_NODES 50000
#define N_EDGES 800000
#define DIM 128
#define N_GRAPHS 512
#define NBUCK ((N_NODES + 63) / 64)      // 782 buckets of 64 nodes
#define SC_CH 16384                       // edges per scatter block

typedef unsigned int uint;
typedef unsigned short ushort;
typedef __attribute__((ext_vector_type(8))) short short8;   // 8 x bf16 MFMA frag
typedef __attribute__((ext_vector_type(4))) float f32x4;    // MFMA C/D frag

// blocked feature layout: HSB[p][node][16 uints] = cols [32p, 32p+32) of node
#define HSB_IDX(p, node, u) ((((size_t)(p) * N_NODES) + (node)) * 16 + (u))

__device__ __forceinline__ ushort f2bf(float f) {
    uint u = __float_as_uint(f);
    uint r = (u + 0x7FFF + ((u >> 16) & 1)) >> 16;   // round-to-nearest-even
    return (ushort)r;
}
__device__ __forceinline__ uint pack2(float a, float b) {
    return (uint)f2bf(a) | ((uint)f2bf(b) << 16);
}
__device__ __forceinline__ float2 unpack2(uint v) {
    return make_float2(__uint_as_float(v << 16), __uint_as_float(v & 0xFFFF0000u));
}

// ---------------- init: zero bucketCnt + W -> MFMA B-frag order ----------------
// Wfrag uint index r = ((ct*4+kc)*64 + lane)*4 + j2 ; element j=2*j2(+1) has
// k = kc*32 + (lane>>4)*8 + j , n = ct*16 + (lane&15).

__global__ __launch_bounds__(256) void k_init(const float* __restrict__ W1,
                                              const float* __restrict__ W2,
                                              uint* __restrict__ wf1,
                                              uint* __restrict__ wf2,
                                              int* __restrict__ bucketCnt) {
    int t = blockIdx.x * 256 + threadIdx.x;      // 64 blocks -> [0, 16384)
    if (t < NBUCK) bucketCnt[t] = 0;
    const float* W = (t < 8192) ? W1 : W2;
    uint* dst = (t < 8192) ? wf1 : wf2;
    int r = t & 8191;
    int j2 = r & 3;
    int lane = (r >> 2) & 63;
    int tk = r >> 8;                 // ct*4+kc
    int kc = tk & 3, ct = tk >> 2;
    int j = j2 * 2;
    int k = kc * 32 + (lane >> 4) * 8 + j;
    int n = ct * 16 + (lane & 15);
    dst[r] = pack2(W[k * 128 + n], W[(k + 1) * 128 + n]);
}

// ---------------- bucketed CSR build ----------------

__global__ __launch_bounds__(1024) void k_bcount(const int* __restrict__ ei,
                                                 int* __restrict__ bucketCnt, int E) {
    __shared__ int h[NBUCK];
    int tid = threadIdx.x;
    for (int t = tid; t < NBUCK; t += 1024) h[t] = 0;
    __syncthreads();
    for (int e = blockIdx.x * 1024 + tid; e < E; e += gridDim.x * 1024)
        atomicAdd(&h[ei[E + e] >> 6], 1);
    __syncthreads();
    for (int t = tid; t < NBUCK; t += 1024) {
        int c = h[t];
        if (c) atomicAdd(&bucketCnt[t], c);
    }
}

__global__ __launch_bounds__(1024) void k_bscan(const int* __restrict__ bucketCnt,
                                                int* __restrict__ bucketStart,
                                                int* __restrict__ bucketCursor) {
    __shared__ int wsum[16];
    int tid = threadIdx.x;
    int lane = tid & 63, wv = tid >> 6;
    int v = (tid < NBUCK) ? bucketCnt[tid] : 0;
    int s = v;
    #pragma unroll
    for (int off = 1; off < 64; off <<= 1) {
        int u = __shfl_up(s, off, 64);
        if (lane >= off) s += u;
    }
    if (lane == 63) wsum[wv] = s;
    __syncthreads();
    int woff = 0;
    #pragma unroll
    for (int w = 0; w < 16; ++w) woff += (w < wv) ? wsum[w] : 0;
    int excl = woff + s - v;
    if (tid < NBUCK) {
        bucketStart[tid] = excl;
        bucketCursor[tid] = excl;
    }
    if (tid == 1023) {
        int tot = 0;
        #pragma unroll
        for (int w = 0; w < 16; ++w) tot += wsum[w];
        bucketStart[NBUCK] = tot;
    }
}

// scatter packed (src | dstlocal<<16) into bucket regions
__global__ __launch_bounds__(1024) void k_bscatter(const int* __restrict__ ei,
                                                   int* __restrict__ bucketCursor,
                                                   uint* __restrict__ epk, int E) {
    __shared__ int hc[NBUCK];
    __shared__ int hbase[NBUCK];
    int tid = threadIdx.x;
    int e0 = blockIdx.x * SC_CH;
    int e1 = min(e0 + SC_CH, E);
    for (int t = tid; t < NBUCK; t += 1024) hc[t] = 0;
    __syncthreads();
    for (int e = e0 + tid; e < e1; e += 1024)
        atomicAdd(&hc[ei[E + e] >> 6], 1);
    __syncthreads();
    for (int t = tid; t < NBUCK; t += 1024) {
        int c = hc[t];
        hbase[t] = c ? atomicAdd(&bucketCursor[t], c) : 0;
        hc[t] = 0;
    }
    __syncthreads();
    for (int e = e0 + tid; e < e1; e += 1024) {
        int s = ei[e], d = ei[E + e];
        int b = d >> 6;
        int off = atomicAdd(&hc[b], 1);
        epk[hbase[b] + off] = (uint)s | ((uint)(d & 63) << 16);
    }
}

// per-bucket local CSR fill
__global__ __launch_bounds__(256) void k_localcsr(const uint* __restrict__ epk,
                                                  const int* __restrict__ bucketStart,
                                                  int* __restrict__ rowStart,
                                                  float* __restrict__ dinv,
                                                  int* __restrict__ csr) {
    __shared__ int cnt[64];
    __shared__ int cur[64];
    int tid = threadIdx.x;
    int b = blockIdx.x;
    int b0 = b << 6;
    int s = bucketStart[b], e = bucketStart[b + 1];
    if (tid < 64) cnt[tid] = 0;
    __syncthreads();
    for (int i = s + tid; i < e; i += 256)
        atomicAdd(&cnt[epk[i] >> 16], 1);
    __syncthreads();
    if (tid < 64) {   // wave 0: 64-wide exclusive scan
        int c = cnt[tid];
        int sc = c;
        #pragma unroll
        for (int off = 1; off < 64; off <<= 1) {
            int u = __shfl_up(sc, off, 64);
            if (tid >= off) sc += u;
        }
        int excl = sc - c;
        int node = b0 + tid;
        if (node < N_NODES) {
            rowStart[node] = s + excl;
            dinv[node] = rsqrtf((float)c + 1.0f);
        }
        cur[tid] = s + excl;
    }
    if (tid == 0 && b == NBUCK - 1) rowStart[N_NODES] = e;
    __syncthreads();
    for (int i = s + tid; i < e; i += 256) {
        uint p = epk[i];
        int pos = atomicAdd(&cur[p >> 16], 1);
        csr[pos] = (int)(p & 0xFFFFu);
    }
}

// ---------------- MFMA GEMM: HSB_out[r,:] = bf16(X[r,:]) @ Wfrag * dinv[r] ----------
// 4 waves/block, each wave owns a 16-row strip x 128 cols. No LDS.

template<bool BF16IN>
__global__ __launch_bounds__(256) void k_lin_mfma(const void* __restrict__ Xv,
                                                  const uint* __restrict__ Wfrag,
                                                  const float* __restrict__ dinv,
                                                  uint* __restrict__ out, int N) {
    int wv = threadIdx.x >> 6, lane = threadIdx.x & 63;
    int strip = blockIdx.x * 4 + wv;
    int row0 = strip * 16;
    if (row0 >= N) return;
    int m = lane & 15;        // A-row / D-col within tile
    int kg = lane >> 4;       // k-group
    int arow = row0 + m;
    bool valid = arow < N;

    short8 af[4];
    if constexpr (!BF16IN) {
        const float* X = (const float*)Xv;
        const float* base = X + (size_t)arow * DIM + kg * 8;
        #pragma unroll
        for (int kc = 0; kc < 4; ++kc) {
            float4 a0 = make_float4(0.f, 0.f, 0.f, 0.f), a1 = a0;
            if (valid) {
                a0 = *(const float4*)(base + kc * 32);
                a1 = *(const float4*)(base + kc * 32 + 4);
            }
            short8 f;
            f[0] = (short)f2bf(a0.x); f[1] = (short)f2bf(a0.y);
            f[2] = (short)f2bf(a0.z); f[3] = (short)f2bf(a0.w);
            f[4] = (short)f2bf(a1.x); f[5] = (short)f2bf(a1.y);
            f[6] = (short)f2bf(a1.z); f[7] = (short)f2bf(a1.w);
            af[kc] = f;
        }
    } else {
        // blocked input: cols kc*32 + kg*8 .. +8 live in slice p=kc, uints kg*4..+4
        const uint* X = (const uint*)Xv;
        #pragma unroll
        for (int kc = 0; kc < 4; ++kc) {
            union { uint4 u; short8 s; } cv;
            cv.u = valid ? *(const uint4*)(X + HSB_IDX(kc, arow, kg * 4))
                         : make_uint4(0, 0, 0, 0);
            af[kc] = cv.s;
        }
    }

    f32x4 acc[8];
    #pragma unroll
    for (int ct = 0; ct < 8; ++ct) acc[ct] = (f32x4){0.f, 0.f, 0.f, 0.f};

    #pragma unroll
    for (int ct = 0; ct < 8; ++ct) {
        #pragma unroll
        for (int kc = 0; kc < 4; ++kc) {
            union { uint4 u; short8 s; } bv;
            bv.u = *(const uint4*)(Wfrag + ((size_t)(ct * 4 + kc) * 64 + lane) * 4);
            acc[ct] = __builtin_amdgcn_mfma_f32_16x16x32_bf16(af[kc], bv.s, acc[ct], 0, 0, 0);
        }
    }

    // epilogue into blocked layout: D row = kg*4+reg, col = ct*16+m -> slice col>>5
    ushort* ob = (ushort*)out;
    #pragma unroll
    for (int reg = 0; reg < 4; ++reg) {
        int orow = row0 + kg * 4 + reg;
        if (orow < N) {
            float di = dinv[orow];
            #pragma unroll
            for (int ct = 0; ct < 8; ++ct) {
                int col = ct * 16 + m;
                int p = col >> 5, cb = col & 31;
                ob[((size_t)p * N_NODES + orow) * 32 + cb] = f2bf(acc[ct][reg] * di);
            }
        }
    }
}

// ---------------- Column-blocked aggregation ----------------
// grid (ceil(n/4), 4): blockIdx.y = slice p (swept slowly -> slice stays L2-hot).
// wave = one node; lane = (edge-group eg = lane>>4) x (l16 = lane&15 -> uint within slice).
// 4 edges in flight, 64B (one line) per edge-slice gather. xor-fold groups at end.

template<bool FUSE_HEAD>
__global__ __launch_bounds__(256) void k_aggregate(const uint* __restrict__ HS,
                                                   const int* __restrict__ rowStart,
                                                   const int* __restrict__ csr,
                                                   const float* __restrict__ dinv,
                                                   const float* __restrict__ bias,
                                                   const float* __restrict__ Wl,
                                                   uint* __restrict__ outRow,
                                                   float* __restrict__ outY, int n) {
    int wv = threadIdx.x >> 6, lane = threadIdx.x & 63;
    int nid = blockIdx.x * 4 + wv;
    if (nid >= n) return;
    int p = blockIdx.y;
    int l16 = lane & 15, eg = lane >> 4;

    float2 acc = make_float2(0.f, 0.f);
    if (eg == 0) acc = unpack2(HS[HSB_IDX(p, nid, l16)]);   // self contribution

    int beg = rowStart[nid], end = rowStart[nid + 1];
    for (int e = beg + eg; e < end; e += 4) {
        int src = csr[e];
        float2 f = unpack2(HS[HSB_IDX(p, src, l16)]);
        acc.x += f.x;
        acc.y += f.y;
    }
    // fold the 4 edge-groups
    acc.x += __shfl_xor(acc.x, 16);
    acc.y += __shfl_xor(acc.y, 16);
    acc.x += __shfl_xor(acc.x, 32);
    acc.y += __shfl_xor(acc.y, 32);

    float di = dinv[nid];
    int c = p * 32 + l16 * 2;
    float ox = fmaxf(acc.x * di + bias[c], 0.f);
    float oy = fmaxf(acc.y * di + bias[c + 1], 0.f);
    if constexpr (!FUSE_HEAD) {
        if (eg == 0) outRow[HSB_IDX(p, nid, l16)] = pack2(ox, oy);
    } else {
        float part = ox * Wl[c] + oy * Wl[c + 1];
        if (eg == 0) {
            part += __shfl_down(part, 8, 16);
            part += __shfl_down(part, 4, 16);
            part += __shfl_down(part, 2, 16);
            part += __shfl_down(part, 1, 16);
            if (l16 == 0) outY[(size_t)p * N_NODES + nid] = part;
        }
    }
}

// ---------------- Pool over per-node head partials (4 slices) ----------------

__global__ __launch_bounds__(64) void k_pool_y(const float* __restrict__ y,
                                               const int* __restrict__ batch,
                                               const float* __restrict__ bl,
                                               float* __restrict__ out, int n) {
    int g = blockIdx.x;
    int lane = threadIdx.x;
    int lo = 0, hi = n;
    while (lo < hi) { int mid = (lo + hi) >> 1; if (batch[mid] < g) lo = mid + 1; else hi = mid; }
    int s = lo;
    hi = n;
    while (lo < hi) { int mid = (lo + hi) >> 1; if (batch[mid] < g + 1) lo = mid + 1; else hi = mid; }
    int e = lo;

    float sum = 0.f;
    for (int i = s + lane; i < e; i += 64)
        sum += (y[i] + y[N_NODES + i]) + (y[2 * N_NODES + i] + y[3 * N_NODES + i]);
    #pragma unroll
    for (int off = 32; off > 0; off >>= 1) sum += __shfl_down(sum, off, 64);
    if (lane == 0) out[g] = sum / fmaxf((float)(e - s), 1.0f) + bl[0];
}

// ---------------- launch ----------------

extern "C" void kernel_launch(void* const* d_in, const int* in_sizes, int n_in,
                              void* d_out, int out_size, void* d_ws, size_t ws_size,
                              hipStream_t stream) {
    const float* x  = (const float*)d_in[0];
    const int*   ei = (const int*)d_in[1];
    const int*   batch = (const int*)d_in[2];
    const float* W1 = (const float*)d_in[3];
    const float* b1 = (const float*)d_in[4];
    const float* W2 = (const float*)d_in[5];
    const float* b2 = (const float*)d_in[6];
    const float* Wl = (const float*)d_in[7];
    const float* bl = (const float*)d_in[8];
    float* out = (float*)d_out;

    // workspace layout (uint units; starts kept 16B-aligned)
    uint* hs  = (uint*)d_ws;                             // 4*N*16 (blocked bf16 rows)
    uint* h2b = hs + (size_t)N_NODES * 64;               // 4*N*16
    float* dinv = (float*)(h2b + (size_t)N_NODES * 64);  // N
    float* ynode = dinv + N_NODES;                       // 4*N
    int* rowStart = (int*)(ynode + 4 * N_NODES);         // N+4
    int* bucketCnt = rowStart + N_NODES + 4;             // 784
    int* bucketStart = bucketCnt + 784;                  // 784
    int* bucketCursor = bucketStart + 784;               // 784
    int* csr = bucketCursor + 784;                       // E
    uint* epk = (uint*)(csr + N_EDGES);                  // E packed pairs
    uint* wf1 = epk + N_EDGES;                           // 8192
    uint* wf2 = wf1 + 8192;                              // 8192

    // 0. init: zero bucketCnt + weight conversion
    k_init<<<64, 256, 0, stream>>>(W1, W2, wf1, wf2, bucketCnt);

    // 1. bucketed CSR build
    k_bcount<<<64, 1024, 0, stream>>>(ei, bucketCnt, N_EDGES);
    k_bscan<<<1, 1024, 0, stream>>>(bucketCnt, bucketStart, bucketCursor);
    k_bscatter<<<(N_EDGES + SC_CH - 1) / SC_CH, 1024, 0, stream>>>(ei, bucketCursor, epk, N_EDGES);
    k_localcsr<<<NBUCK, 256, 0, stream>>>(epk, bucketStart, rowStart, dinv, csr);

    int strips = (N_NODES + 15) / 16;                    // 3125
    int gemmGrid = (strips + 3) / 4;                     // 782
    dim3 aggGrid((N_NODES + 3) / 4, 4);

    // 2. layer 1
    k_lin_mfma<false><<<gemmGrid, 256, 0, stream>>>(x, wf1, dinv, hs, N_NODES);
    k_aggregate<false><<<aggGrid, 256, 0, stream>>>(hs, rowStart, csr, dinv, b1, Wl, h2b, ynode, N_NODES);

    // 3. layer 2 (head fused into aggregation)
    k_lin_mfma<true><<<gemmGrid, 256, 0, stream>>>(h2b, wf2, dinv, hs, N_NODES);
    k_aggregate<true><<<aggGrid, 256, 0, stream>>>(hs, rowStart, csr, dinv, b2, Wl, h2b, ynode, N_NODES);

    // 4. pool + head bias
    k_pool_y<<<N_GRAPHS, 64, 0, stream>>>(ynode, batch, bl, out, N_NODES);
}

// Round 8
// 151.758 us; speedup vs baseline: 1.8952x; 1.8952x over previous
//
#include <hip/hip_runtime.h>
#include <hip/hip_bf16.h>

#define N_NODES 50000
#define N_EDGES 800000
#define DIM 128
#define N_GRAPHS 512
#define NBUCK ((N_NODES + 63) / 64)      // 782 buckets of 64 nodes
#define SC_CH 16384                       // edges per scatter block

typedef unsigned int uint;
typedef unsigned short ushort;
typedef __attribute__((ext_vector_type(8))) short short8;   // 8 x bf16 MFMA frag
typedef __attribute__((ext_vector_type(4))) float f32x4;    // MFMA C/D frag

__device__ __forceinline__ ushort f2bf(float f) {
    uint u = __float_as_uint(f);
    uint r = (u + 0x7FFF + ((u >> 16) & 1)) >> 16;   // round-to-nearest-even
    return (ushort)r;
}
__device__ __forceinline__ uint pack2(float a, float b) {
    return (uint)f2bf(a) | ((uint)f2bf(b) << 16);
}
__device__ __forceinline__ float2 unpack2(uint v) {
    return make_float2(__uint_as_float(v << 16), __uint_as_float(v & 0xFFFF0000u));
}

// ---------------- init: zero bucketCnt + W -> MFMA B-frag order ----------------
// Wfrag uint index r = ((ct*4+kc)*64 + lane)*4 + j2 ; element j=2*j2(+1) has
// k = kc*32 + (lane>>4)*8 + j , n = ct*16 + (lane&15).

__global__ __launch_bounds__(256) void k_init(const float* __restrict__ W1,
                                              const float* __restrict__ W2,
                                              uint* __restrict__ wf1,
                                              uint* __restrict__ wf2,
                                              int* __restrict__ bucketCnt) {
    int t = blockIdx.x * 256 + threadIdx.x;      // 64 blocks -> [0, 16384)
    if (t < NBUCK) bucketCnt[t] = 0;
    const float* W = (t < 8192) ? W1 : W2;
    uint* dst = (t < 8192) ? wf1 : wf2;
    int r = t & 8191;
    int j2 = r & 3;
    int lane = (r >> 2) & 63;
    int tk = r >> 8;                 // ct*4+kc
    int kc = tk & 3, ct = tk >> 2;
    int j = j2 * 2;
    int k = kc * 32 + (lane >> 4) * 8 + j;
    int n = ct * 16 + (lane & 15);
    dst[r] = pack2(W[k * 128 + n], W[(k + 1) * 128 + n]);
}

// ---------------- bucketed CSR build ----------------

__global__ __launch_bounds__(1024) void k_bcount(const int* __restrict__ ei,
                                                 int* __restrict__ bucketCnt, int E) {
    __shared__ int h[NBUCK];
    int tid = threadIdx.x;
    for (int t = tid; t < NBUCK; t += 1024) h[t] = 0;
    __syncthreads();
    for (int e = blockIdx.x * 1024 + tid; e < E; e += gridDim.x * 1024)
        atomicAdd(&h[ei[E + e] >> 6], 1);
    __syncthreads();
    for (int t = tid; t < NBUCK; t += 1024) {
        int c = h[t];
        if (c) atomicAdd(&bucketCnt[t], c);
    }
}

__global__ __launch_bounds__(1024) void k_bscan(const int* __restrict__ bucketCnt,
                                                int* __restrict__ bucketStart,
                                                int* __restrict__ bucketCursor) {
    __shared__ int wsum[16];
    int tid = threadIdx.x;
    int lane = tid & 63, wv = tid >> 6;
    int v = (tid < NBUCK) ? bucketCnt[tid] : 0;
    int s = v;
    #pragma unroll
    for (int off = 1; off < 64; off <<= 1) {
        int u = __shfl_up(s, off, 64);
        if (lane >= off) s += u;
    }
    if (lane == 63) wsum[wv] = s;
    __syncthreads();
    int woff = 0;
    #pragma unroll
    for (int w = 0; w < 16; ++w) woff += (w < wv) ? wsum[w] : 0;
    int excl = woff + s - v;
    if (tid < NBUCK) {
        bucketStart[tid] = excl;
        bucketCursor[tid] = excl;
    }
    if (tid == 1023) {
        int tot = 0;
        #pragma unroll
        for (int w = 0; w < 16; ++w) tot += wsum[w];
        bucketStart[NBUCK] = tot;
    }
}

// scatter packed (src | dstlocal<<16) into bucket regions
__global__ __launch_bounds__(1024) void k_bscatter(const int* __restrict__ ei,
                                                   int* __restrict__ bucketCursor,
                                                   uint* __restrict__ epk, int E) {
    __shared__ int hc[NBUCK];
    __shared__ int hbase[NBUCK];
    int tid = threadIdx.x;
    int e0 = blockIdx.x * SC_CH;
    int e1 = min(e0 + SC_CH, E);
    for (int t = tid; t < NBUCK; t += 1024) hc[t] = 0;
    __syncthreads();
    for (int e = e0 + tid; e < e1; e += 1024)
        atomicAdd(&hc[ei[E + e] >> 6], 1);
    __syncthreads();
    for (int t = tid; t < NBUCK; t += 1024) {
        int c = hc[t];
        hbase[t] = c ? atomicAdd(&bucketCursor[t], c) : 0;
        hc[t] = 0;
    }
    __syncthreads();
    for (int e = e0 + tid; e < e1; e += 1024) {
        int s = ei[e], d = ei[E + e];
        int b = d >> 6;
        int off = atomicAdd(&hc[b], 1);
        epk[hbase[b] + off] = (uint)s | ((uint)(d & 63) << 16);
    }
}

// per-bucket local CSR fill
__global__ __launch_bounds__(256) void k_localcsr(const uint* __restrict__ epk,
                                                  const int* __restrict__ bucketStart,
                                                  int* __restrict__ rowStart,
                                                  float* __restrict__ dinv,
                                                  int* __restrict__ csr) {
    __shared__ int cnt[64];
    __shared__ int cur[64];
    int tid = threadIdx.x;
    int b = blockIdx.x;
    int b0 = b << 6;
    int s = bucketStart[b], e = bucketStart[b + 1];
    if (tid < 64) cnt[tid] = 0;
    __syncthreads();
    for (int i = s + tid; i < e; i += 256)
        atomicAdd(&cnt[epk[i] >> 16], 1);
    __syncthreads();
    if (tid < 64) {   // wave 0: 64-wide exclusive scan
        int c = cnt[tid];
        int sc = c;
        #pragma unroll
        for (int off = 1; off < 64; off <<= 1) {
            int u = __shfl_up(sc, off, 64);
            if (tid >= off) sc += u;
        }
        int excl = sc - c;
        int node = b0 + tid;
        if (node < N_NODES) {
            rowStart[node] = s + excl;
            dinv[node] = rsqrtf((float)c + 1.0f);
        }
        cur[tid] = s + excl;
    }
    if (tid == 0 && b == NBUCK - 1) rowStart[N_NODES] = e;
    __syncthreads();
    for (int i = s + tid; i < e; i += 256) {
        uint p = epk[i];
        int pos = atomicAdd(&cur[p >> 16], 1);
        csr[pos] = (int)(p & 0xFFFFu);
    }
}

// ---------------- MFMA GEMM: out_bf16[r,:] = bf16(X[r,:]) @ Wfrag * dinv[r] ----------
// 4 waves/block, each wave owns a 16-row strip x 128 cols. No LDS. Row-major bf16 out.

template<bool BF16IN>
__global__ __launch_bounds__(256) void k_lin_mfma(const void* __restrict__ Xv,
                                                  const uint* __restrict__ Wfrag,
                                                  const float* __restrict__ dinv,
                                                  uint* __restrict__ out, int N) {
    int wv = threadIdx.x >> 6, lane = threadIdx.x & 63;
    int strip = blockIdx.x * 4 + wv;
    int row0 = strip * 16;
    if (row0 >= N) return;
    int m = lane & 15;        // A-row / D-col within tile
    int kg = lane >> 4;       // k-group
    int arow = row0 + m;
    bool valid = arow < N;

    short8 af[4];
    if constexpr (!BF16IN) {
        const float* X = (const float*)Xv;
        const float* base = X + (size_t)arow * DIM + kg * 8;
        #pragma unroll
        for (int kc = 0; kc < 4; ++kc) {
            float4 a0 = make_float4(0.f, 0.f, 0.f, 0.f), a1 = a0;
            if (valid) {
                a0 = *(const float4*)(base + kc * 32);
                a1 = *(const float4*)(base + kc * 32 + 4);
            }
            short8 f;
            f[0] = (short)f2bf(a0.x); f[1] = (short)f2bf(a0.y);
            f[2] = (short)f2bf(a0.z); f[3] = (short)f2bf(a0.w);
            f[4] = (short)f2bf(a1.x); f[5] = (short)f2bf(a1.y);
            f[6] = (short)f2bf(a1.z); f[7] = (short)f2bf(a1.w);
            af[kc] = f;
        }
    } else {
        const uint* X = (const uint*)Xv;
        const uint* base = X + (size_t)arow * 64 + kg * 4;
        #pragma unroll
        for (int kc = 0; kc < 4; ++kc) {
            union { uint4 u; short8 s; } cv;
            cv.u = valid ? *(const uint4*)(base + kc * 16) : make_uint4(0, 0, 0, 0);
            af[kc] = cv.s;
        }
    }

    f32x4 acc[8];
    #pragma unroll
    for (int ct = 0; ct < 8; ++ct) acc[ct] = (f32x4){0.f, 0.f, 0.f, 0.f};

    #pragma unroll
    for (int ct = 0; ct < 8; ++ct) {
        #pragma unroll
        for (int kc = 0; kc < 4; ++kc) {
            union { uint4 u; short8 s; } bv;
            bv.u = *(const uint4*)(Wfrag + ((size_t)(ct * 4 + kc) * 64 + lane) * 4);
            acc[ct] = __builtin_amdgcn_mfma_f32_16x16x32_bf16(af[kc], bv.s, acc[ct], 0, 0, 0);
        }
    }

    // epilogue: D row = kg*4 + reg, col = ct*16 + m
    ushort* ob = (ushort*)out;
    #pragma unroll
    for (int reg = 0; reg < 4; ++reg) {
        int orow = row0 + kg * 4 + reg;
        if (orow < N) {
            float di = dinv[orow];
            size_t rb = (size_t)orow * DIM + m;
            #pragma unroll
            for (int ct = 0; ct < 8; ++ct)
                ob[rb + ct * 16] = f2bf(acc[ct][reg] * di);
        }
    }
}

// ---------------- Aggregation (bf16 rows, f32 accumulate) ----------------
// one wave per node; lane holds cols (2l, 2l+1) packed bf16. 8-wide edge unroll.
// FUSE_HEAD=false: write post-relu row bf16.  true: write y[nid]=relu_row.Wl.

template<bool FUSE_HEAD>
__global__ __launch_bounds__(256) void k_aggregate(const uint* __restrict__ HS,
                                                   const int* __restrict__ rowStart,
                                                   const int* __restrict__ csr,
                                                   const float* __restrict__ dinv,
                                                   const float* __restrict__ bias,
                                                   const float* __restrict__ Wl,
                                                   uint* __restrict__ outRow,
                                                   float* __restrict__ outY, int n) {
    int wv = threadIdx.x >> 6, lane = threadIdx.x & 63;
    int nid = blockIdx.x * 4 + wv;
    if (nid >= n) return;
    float2 acc = unpack2(HS[(size_t)nid * 64 + lane]);   // self contribution
    int beg = rowStart[nid], end = rowStart[nid + 1];
    int e = beg;
    for (; e + 7 < end; e += 8) {
        int s0 = csr[e],     s1 = csr[e + 1], s2 = csr[e + 2], s3 = csr[e + 3];
        int s4 = csr[e + 4], s5 = csr[e + 5], s6 = csr[e + 6], s7 = csr[e + 7];
        float2 f0 = unpack2(HS[(size_t)s0 * 64 + lane]);
        float2 f1 = unpack2(HS[(size_t)s1 * 64 + lane]);
        float2 f2 = unpack2(HS[(size_t)s2 * 64 + lane]);
        float2 f3 = unpack2(HS[(size_t)s3 * 64 + lane]);
        float2 f4 = unpack2(HS[(size_t)s4 * 64 + lane]);
        float2 f5 = unpack2(HS[(size_t)s5 * 64 + lane]);
        float2 f6 = unpack2(HS[(size_t)s6 * 64 + lane]);
        float2 f7 = unpack2(HS[(size_t)s7 * 64 + lane]);
        acc.x += ((f0.x + f1.x) + (f2.x + f3.x)) + ((f4.x + f5.x) + (f6.x + f7.x));
        acc.y += ((f0.y + f1.y) + (f2.y + f3.y)) + ((f4.y + f5.y) + (f6.y + f7.y));
    }
    for (; e + 1 < end; e += 2) {
        int s0 = csr[e], s1 = csr[e + 1];
        float2 f0 = unpack2(HS[(size_t)s0 * 64 + lane]);
        float2 f1 = unpack2(HS[(size_t)s1 * 64 + lane]);
        acc.x += f0.x + f1.x;
        acc.y += f0.y + f1.y;
    }
    if (e < end) {
        float2 f0 = unpack2(HS[(size_t)csr[e] * 64 + lane]);
        acc.x += f0.x;
        acc.y += f0.y;
    }
    float di = dinv[nid];
    int c = lane * 2;
    float ox = fmaxf(acc.x * di + bias[c], 0.f);
    float oy = fmaxf(acc.y * di + bias[c + 1], 0.f);
    if constexpr (!FUSE_HEAD) {
        outRow[(size_t)nid * 64 + lane] = pack2(ox, oy);
    } else {
        float part = ox * Wl[c] + oy * Wl[c + 1];
        #pragma unroll
        for (int off = 32; off > 0; off >>= 1) part += __shfl_down(part, off, 64);
        if (lane == 0) outY[nid] = part;
    }
}

// ---------------- Pool over per-node head values ----------------

__global__ __launch_bounds__(64) void k_pool_y(const float* __restrict__ y,
                                               const int* __restrict__ batch,
                                               const float* __restrict__ bl,
                                               float* __restrict__ out, int n) {
    int g = blockIdx.x;
    int lane = threadIdx.x;
    int lo = 0, hi = n;
    while (lo < hi) { int mid = (lo + hi) >> 1; if (batch[mid] < g) lo = mid + 1; else hi = mid; }
    int s = lo;
    hi = n;
    while (lo < hi) { int mid = (lo + hi) >> 1; if (batch[mid] < g + 1) lo = mid + 1; else hi = mid; }
    int e = lo;

    float sum = 0.f;
    for (int i = s + lane; i < e; i += 64) sum += y[i];
    #pragma unroll
    for (int off = 32; off > 0; off >>= 1) sum += __shfl_down(sum, off, 64);
    if (lane == 0) out[g] = sum / fmaxf((float)(e - s), 1.0f) + bl[0];
}

// ---------------- launch ----------------

extern "C" void kernel_launch(void* const* d_in, const int* in_sizes, int n_in,
                              void* d_out, int out_size, void* d_ws, size_t ws_size,
                              hipStream_t stream) {
    const float* x  = (const float*)d_in[0];
    const int*   ei = (const int*)d_in[1];
    const int*   batch = (const int*)d_in[2];
    const float* W1 = (const float*)d_in[3];
    const float* b1 = (const float*)d_in[4];
    const float* W2 = (const float*)d_in[5];
    const float* b2 = (const float*)d_in[6];
    const float* Wl = (const float*)d_in[7];
    const float* bl = (const float*)d_in[8];
    float* out = (float*)d_out;

    // workspace layout (uint units; starts kept 16B-aligned)
    uint* hs  = (uint*)d_ws;                             // N*64 (bf16 x128 rows)
    uint* h2b = hs + (size_t)N_NODES * 64;               // N*64
    float* dinv = (float*)(h2b + (size_t)N_NODES * 64);  // N
    float* ynode = dinv + N_NODES;                       // N
    int* rowStart = (int*)(ynode + N_NODES);             // N+4
    int* bucketCnt = rowStart + N_NODES + 4;             // 784
    int* bucketStart = bucketCnt + 784;                  // 784
    int* bucketCursor = bucketStart + 784;               // 784
    int* csr = bucketCursor + 784;                       // E
    uint* epk = (uint*)(csr + N_EDGES);                  // E packed pairs
    uint* wf1 = epk + N_EDGES;                           // 8192
    uint* wf2 = wf1 + 8192;                              // 8192

    // 0. init: zero bucketCnt + weight conversion
    k_init<<<64, 256, 0, stream>>>(W1, W2, wf1, wf2, bucketCnt);

    // 1. bucketed CSR build
    k_bcount<<<64, 1024, 0, stream>>>(ei, bucketCnt, N_EDGES);
    k_bscan<<<1, 1024, 0, stream>>>(bucketCnt, bucketStart, bucketCursor);
    k_bscatter<<<(N_EDGES + SC_CH - 1) / SC_CH, 1024, 0, stream>>>(ei, bucketCursor, epk, N_EDGES);
    k_localcsr<<<NBUCK, 256, 0, stream>>>(epk, bucketStart, rowStart, dinv, csr);

    int strips = (N_NODES + 15) / 16;                    // 3125
    int gemmGrid = (strips + 3) / 4;                     // 782
    int aggGrid  = (N_NODES + 3) / 4;

    // 2. layer 1
    k_lin_mfma<false><<<gemmGrid, 256, 0, stream>>>(x, wf1, dinv, hs, N_NODES);
    k_aggregate<false><<<aggGrid, 256, 0, stream>>>(hs, rowStart, csr, dinv, b1, Wl, h2b, ynode, N_NODES);

    // 3. layer 2 (head fused into aggregation)
    k_lin_mfma<true><<<gemmGrid, 256, 0, stream>>>(h2b, wf2, dinv, hs, N_NODES);
    k_aggregate<true><<<aggGrid, 256, 0, stream>>>(hs, rowStart, csr, dinv, b2, Wl, h2b, ynode, N_NODES);

    // 4. pool + head bias
    k_pool_y<<<N_GRAPHS, 64, 0, stream>>>(ynode, batch, bl, out, N_NODES);
}